// Round 9
// baseline (167.473 us; speedup 1.0000x reference)
//
#include <hip/hip_runtime.h>

#define NN 512
#define DIN 64
#define DH 32
#define HT 264    // h_t row stride for 256 local rows (+8 pad)

typedef __attribute__((ext_vector_type(8))) short short8;
typedef __attribute__((ext_vector_type(4))) short short4v;
typedef __attribute__((ext_vector_type(4))) float f32x4;

__device__ __forceinline__ float bf2f(unsigned short u) {
    return __uint_as_float(((unsigned)u) << 16);
}
__device__ __forceinline__ unsigned short f2bf(float x) {
    unsigned u = __float_as_uint(x);
    u += 0x7FFF + ((u >> 16) & 1);
    return (unsigned short)(u >> 16);
}

// Two blocks per (head,batch) split BY J-HALF (not i-rows): scores come from
// x @ (W a) so neither block needs the other's projection — no duplicated
// heavy work (R7's mistake). 512 threads, NO launch-bounds min-waves and NO
// 1024-thread blocks: both made the allocator jump to the 64-VGPR tier and
// spill (R6: FETCH 54/WRITE 91 MB; R8: 53/89 MB). This shape allocated 88
// VGPR spill-free in R3/R5 -> 2 blocks/CU = 4 waves/SIMD.
// Outputs RAW partial numerator + partial denominator; gru combines.
__global__ __launch_bounds__(512) void attn_kernel(
    const float* __restrict__ in_g,    // [B,512,64]
    const float* __restrict__ lin_g,   // [H,64,32]
    const float* __restrict__ asrc_g,  // [H,32]
    const float* __restrict__ atar_g,  // [H,32]
    float* __restrict__ numer,         // [512 slices][512][32] raw partial sums
    float* __restrict__ denom)         // [512 slices][512] raw partial denominators
{
    __shared__ unsigned short h_t[DH * HT];          // 16896 B: h_t[c*HT + jloc]
    __shared__ float wsv[DIN], wtv[DIN];             // W @ a_src, W @ a_tar
    __shared__ float s_arr[256], e1s[256], e2s[256]; // local j-half: s, e^s, e^{0.2s}
    __shared__ float cng[NN], e1t[NN], e2t[NN];      // all i: -t, e^t, e^{0.2t}

    const int t = threadIdx.x;
    const int lane = t & 63, wv = t >> 6;
    const int l15 = lane & 15, quad = lane >> 4;
    const int jh   = blockIdx.x & 1;                 // j-half
    const int hIdx = (blockIdx.x >> 1) & 7;
    const int bIdx = blockIdx.x >> 4;
    const int slice = blockIdx.x;

    // ---------- A0a: project attention vectors through W (64x32 each) ----------
    if (t < 128) {
        int d = t & 63;
        const float* av = (t < 64) ? (asrc_g + hIdx * 32) : (atar_g + hIdx * 32);
        const float* lp = lin_g + hIdx * (DIN * DH) + d * DH;
        float a = 0.f;
        #pragma unroll
        for (int k = 0; k < 32; ++k) a += lp[k] * av[k];
        if (t < 64) wsv[d] = a; else wtv[d] = a;
    }
    __syncthreads();

    // ---------- A0b: s,t for all 512 rows directly from x (fp32) ----------
    const float* xb = in_g + (size_t)bIdx * (NN * DIN);
    {
        int r = t;                                   // 512 rows, 512 threads
        const float* xr = xb + r * DIN;
        float ds = 0.f, dt = 0.f;
        for (int d0 = 0; d0 < DIN; d0 += 4) {
            f32x4 xv = *(const f32x4*)(xr + d0);
            #pragma unroll
            for (int j = 0; j < 4; ++j) {
                ds += xv[j] * wsv[d0 + j];
                dt += xv[j] * wtv[d0 + j];
            }
        }
        cng[r] = -dt; e1t[r] = expf(dt); e2t[r] = expf(0.2f * dt);
        int rl = r - jh * 256;
        if ((unsigned)rl < 256u) {
            s_arr[rl] = ds; e1s[rl] = expf(ds); e2s[rl] = expf(0.2f * ds);
        }
    }

    // ---------- A1: projection of THIS half's 256 j-rows (16 M-tiles / 8 waves) ----------
    short8 bfrag[2][2];
    {
        const float* lp = lin_g + hIdx * (DIN * DH);
        for (int nt = 0; nt < 2; ++nt)
            for (int ks = 0; ks < 2; ++ks)
                #pragma unroll
                for (int j = 0; j < 8; ++j)
                    bfrag[nt][ks][j] = (short)f2bf(lp[(ks * 32 + quad * 8 + j) * DH + l15 + nt * 16]);
    }
    for (int mi = 0; mi < 2; ++mi) {
        int mt = wv * 2 + mi;                        // 16 local M-tiles
        int row = jh * 256 + mt * 16 + l15;          // global j-row
        const float* rp = xb + row * DIN + quad * 8;
        f32x4 x0 = *((const f32x4*)rp);
        f32x4 x1 = *((const f32x4*)(rp + 4));
        f32x4 x2 = *((const f32x4*)(rp + 32));
        f32x4 x3 = *((const f32x4*)(rp + 36));
        short8 a0, a1;
        #pragma unroll
        for (int j = 0; j < 4; ++j) {
            a0[j]     = (short)f2bf(x0[j]);
            a0[4 + j] = (short)f2bf(x1[j]);
            a1[j]     = (short)f2bf(x2[j]);
            a1[4 + j] = (short)f2bf(x3[j]);
        }
        f32x4 c0 = {0.f, 0.f, 0.f, 0.f}, c1 = {0.f, 0.f, 0.f, 0.f};
        c0 = __builtin_amdgcn_mfma_f32_16x16x32_bf16(a0, bfrag[0][0], c0, 0, 0, 0);
        c0 = __builtin_amdgcn_mfma_f32_16x16x32_bf16(a1, bfrag[0][1], c0, 0, 0, 0);
        c1 = __builtin_amdgcn_mfma_f32_16x16x32_bf16(a0, bfrag[1][0], c1, 0, 0, 0);
        c1 = __builtin_amdgcn_mfma_f32_16x16x32_bf16(a1, bfrag[1][1], c1, 0, 0, 0);
        #pragma unroll
        for (int r = 0; r < 4; ++r) {
            int mloc = mt * 16 + quad * 4 + r;       // local row 0..255
            h_t[l15 * HT + mloc]        = f2bf(c0[r]);
            h_t[(l15 + 16) * HT + mloc] = f2bf(c1[r]);
        }
    }
    __syncthreads();

    // ---------- B: all 512 i-rows x this half's 256 j (32 row-tiles / 8 waves) ----------
    float cn[4], t1v[4], t2v[4];
    int iR[4], iRl[4];
    #pragma unroll
    for (int rt = 0; rt < 4; ++rt) {
        int rw = (wv * 4 + rt) * 16 + l15;           // global i-row
        iR[rt] = rw; iRl[rt] = rw - jh * 256;
        cn[rt] = cng[rw]; t1v[rt] = e1t[rw]; t2v[rt] = e2t[rw];
    }
    f32x4 acc[4][2];
    float dacc[4];
    #pragma unroll
    for (int rt = 0; rt < 4; ++rt) {
        acc[rt][0] = (f32x4){0.f, 0.f, 0.f, 0.f};
        acc[rt][1] = (f32x4){0.f, 0.f, 0.f, 0.f};
        dacc[rt] = 0.f;
    }

    for (int kb = 0; kb < 8; ++kb) {
        const int j0 = kb * 32 + quad * 8;           // local j
        f32x4 sv0 = *(const f32x4*)&s_arr[j0], sv1 = *(const f32x4*)&s_arr[j0 + 4];
        f32x4 ev0 = *(const f32x4*)&e1s[j0],   ev1 = *(const f32x4*)&e1s[j0 + 4];
        f32x4 fv0 = *(const f32x4*)&e2s[j0],   fv1 = *(const f32x4*)&e2s[j0 + 4];
        short8 b0 = *(const short8*)&h_t[l15 * HT + j0];
        short8 b1 = *(const short8*)&h_t[(l15 + 16) * HT + j0];
        #pragma unroll
        for (int rt = 0; rt < 4; ++rt) {
            const bool selfkb = ((iRl[rt] >> 5) == kb);   // self-edge in this j-tile?
            float w8[8];
            #pragma unroll
            for (int jj = 0; jj < 8; ++jj) {
                float sj = (jj < 4) ? sv0[jj & 3] : sv1[jj & 3];
                float e1 = (jj < 4) ? ev0[jj & 3] : ev1[jj & 3];
                float e2 = (jj < 4) ? fv0[jj & 3] : fv1[jj & 3];
                float w = (sj > cn[rt]) ? t1v[rt] * e1 : t2v[rt] * e2;
                if (selfkb && (j0 + jj == iRl[rt])) w = 0.f;
                dacc[rt] += w;
                w8[jj] = w;
            }
            union { unsigned u[4]; short8 s8; } au;
            #pragma unroll
            for (int pp = 0; pp < 4; ++pp) {
                unsigned lo = __float_as_uint(w8[2 * pp])     + 0x8000u;
                unsigned hi = __float_as_uint(w8[2 * pp + 1]) + 0x8000u;
                au.u[pp] = (lo >> 16) | (hi & 0xffff0000u);
            }
            acc[rt][0] = __builtin_amdgcn_mfma_f32_16x16x32_bf16(au.s8, b0, acc[rt][0], 0, 0, 0);
            acc[rt][1] = __builtin_amdgcn_mfma_f32_16x16x32_bf16(au.s8, b1, acc[rt][1], 0, 0, 0);
        }
    }

    // partial denominator: reduce the 4 quads, write raw
    #pragma unroll
    for (int rt = 0; rt < 4; ++rt) {
        float D = dacc[rt];
        D += __shfl_xor(D, 16, 64);
        D += __shfl_xor(D, 32, 64);
        if (quad == 0) denom[(size_t)slice * NN + iR[rt]] = D;
    }

    // partial numerator, unscaled
    float* nb = numer + (size_t)slice * (NN * DH);
    #pragma unroll
    for (int rt = 0; rt < 4; ++rt) {
        #pragma unroll
        for (int half = 0; half < 2; ++half) {
            #pragma unroll
            for (int r = 0; r < 4; ++r) {
                int row = (wv * 4 + rt) * 16 + quad * 4 + r;
                nb[row * DH + half * 16 + l15] = acc[rt][half][r];
            }
        }
    }
}

// GRU-style gated update. 256 blocks x 256 threads, 64 rows/block.
// Combines the 16 partial slices (8 heads x 2 j-halves) of numer/denom.
__global__ __launch_bounds__(256) void gru_kernel(
    const float* __restrict__ in_g,
    const float* __restrict__ hid_g,
    const float* __restrict__ bias_g,
    const float* __restrict__ Whr, const float* __restrict__ Whi,
    const float* __restrict__ Whm,
    const float* __restrict__ Wir, const float* __restrict__ bir,
    const float* __restrict__ Wii, const float* __restrict__ bii,
    const float* __restrict__ Win, const float* __restrict__ bin_,
    const float* __restrict__ numer,   // [512][512][32]
    const float* __restrict__ denom,   // [512][512]
    float* __restrict__ out_g)
{
    __shared__ float xs[64 * 100];                // cols 0..63 = x, 64..95 = tanh(msum+bias)
    __shared__ unsigned short WtL[3 * 32 * 100];  // Wt[g][k][d] bf16 (96 d's used)
    __shared__ float Dl[64 * 8];                  // 0.125/(D0+D1) per (row,head)

    const int t = threadIdx.x;
    const int rowbase = blockIdx.x * 64;
    const int bslice = blockIdx.x >> 3;           // batch of this block
    const int r0 = (blockIdx.x & 7) * 64;         // row offset within batch

    for (int idx = t; idx < 1024; idx += 256) {
        int fi = idx * 4;
        int row = fi >> 6, d = fi & 63;
        f32x4 v = *(const f32x4*)&in_g[(size_t)(rowbase + row) * 64 + d];
        *(f32x4*)&xs[row * 100 + d] = v;
    }
    for (int idx = t; idx < 512; idx += 256) {    // (row, head) -> combined 1/D
        int row = idx >> 3, h = idx & 7;
        int sl0 = (bslice * 8 + h) * 2;
        float D0 = denom[(size_t)sl0 * NN + (r0 + row)];
        float D1 = denom[(size_t)(sl0 + 1) * NN + (r0 + row)];
        Dl[row * 8 + h] = 0.125f / (D0 + D1);
    }
    for (int idx = t; idx < 9216; idx += 256) {
        int g = idx / 3072, rem = idx % 3072;
        int d = rem >> 5, k2 = rem & 31;
        float v;
        if (g == 0) v = (d < 64) ? Wir[d * 32 + k2] : Whr[(d - 64) * 32 + k2];
        else if (g == 1) v = (d < 64) ? Wii[d * 32 + k2] : Whi[(d - 64) * 32 + k2];
        else v = (d < 64) ? Win[d * 32 + k2] : Whm[(d - 64) * 32 + k2];
        WtL[(g * 32 + k2) * 100 + d] = f2bf(v);
    }
    __syncthreads();
    for (int idx = t; idx < 2048; idx += 256) {   // msum = sum_h (n0+n1)*Dl
        int row = idx >> 5, k2 = idx & 31;
        float ssum = 0.f;
        #pragma unroll
        for (int h = 0; h < 8; ++h) {
            size_t a0 = ((size_t)(bslice * 8 + h) * 2) * (NN * DH) + (size_t)(r0 + row) * DH + k2;
            ssum += (numer[a0] + numer[a0 + (size_t)NN * DH]) * Dl[row * 8 + h];
        }
        xs[row * 100 + 64 + k2] = tanhf(ssum + bias_g[k2]);
    }
    __syncthreads();

    const int k = t & 31, rg = t >> 5;
    const unsigned short* wp0 = &WtL[(0 * 32 + k) * 100];
    const unsigned short* wp1 = &WtL[(1 * 32 + k) * 100];
    const unsigned short* wp2 = &WtL[(2 * 32 + k) * 100];

    float pr[8], pi[8], xn[8], hm[8];
    #pragma unroll
    for (int r = 0; r < 8; ++r) { pr[r] = 0.f; pi[r] = 0.f; xn[r] = 0.f; hm[r] = 0.f; }

    for (int d0 = 0; d0 < 64; d0 += 4) {
        short4v wr4 = *(const short4v*)&wp0[d0];
        short4v wi4 = *(const short4v*)&wp1[d0];
        short4v wn4 = *(const short4v*)&wp2[d0];
        float wr[4], wi[4], wn[4];
        #pragma unroll
        for (int jj = 0; jj < 4; ++jj) {
            wr[jj] = bf2f((unsigned short)wr4[jj]);
            wi[jj] = bf2f((unsigned short)wi4[jj]);
            wn[jj] = bf2f((unsigned short)wn4[jj]);
        }
        #pragma unroll
        for (int r = 0; r < 8; ++r) {
            f32x4 xv = *(const f32x4*)&xs[(rg * 8 + r) * 100 + d0];
            #pragma unroll
            for (int jj = 0; jj < 4; ++jj) {
                pr[r] += xv[jj] * wr[jj];
                pi[r] += xv[jj] * wi[jj];
                xn[r] += xv[jj] * wn[jj];
            }
        }
    }
    for (int d0 = 64; d0 < 96; d0 += 4) {
        short4v wr4 = *(const short4v*)&wp0[d0];
        short4v wi4 = *(const short4v*)&wp1[d0];
        short4v wn4 = *(const short4v*)&wp2[d0];
        float wr[4], wi[4], wn[4];
        #pragma unroll
        for (int jj = 0; jj < 4; ++jj) {
            wr[jj] = bf2f((unsigned short)wr4[jj]);
            wi[jj] = bf2f((unsigned short)wi4[jj]);
            wn[jj] = bf2f((unsigned short)wn4[jj]);
        }
        #pragma unroll
        for (int r = 0; r < 8; ++r) {
            f32x4 xv = *(const f32x4*)&xs[(rg * 8 + r) * 100 + d0];
            #pragma unroll
            for (int jj = 0; jj < 4; ++jj) {
                pr[r] += xv[jj] * wr[jj];
                pi[r] += xv[jj] * wi[jj];
                hm[r] += xv[jj] * wn[jj];
            }
        }
    }

    const float bir_k = bir[k], bii_k = bii[k], bin_k = bin_[k];
    #pragma unroll
    for (int r = 0; r < 8; ++r) {
        int row = rowbase + rg * 8 + r;
        float m  = 1.f / (1.f + expf(-(pr[r] + bir_k)));
        float ig = 1.f / (1.f + expf(-(pi[r] + bii_k)));
        float nn = tanhf(xn[r] + bin_k + m * hm[r]);
        float ho = hid_g[(size_t)row * 32 + k];
        out_g[(size_t)row * 32 + k] = ig * nn + (1.f - ig) * ho;
    }
}

extern "C" void kernel_launch(void* const* d_in, const int* in_sizes, int n_in,
                              void* d_out, int out_size, void* d_ws, size_t ws_size,
                              hipStream_t stream)
{
    const float* inputs = (const float*)d_in[0];
    const float* hidden = (const float*)d_in[1];
    const float* linear = (const float*)d_in[2];
    const float* bias   = (const float*)d_in[3];
    const float* asrc   = (const float*)d_in[4];
    const float* atar   = (const float*)d_in[5];
    const float* Whr    = (const float*)d_in[6];
    const float* Whi    = (const float*)d_in[7];
    const float* Whm    = (const float*)d_in[8];
    const float* Wir    = (const float*)d_in[9];
    const float* bir    = (const float*)d_in[10];
    const float* Wii    = (const float*)d_in[11];
    const float* bii    = (const float*)d_in[12];
    const float* Win    = (const float*)d_in[13];
    const float* bin_   = (const float*)d_in[14];

    float* numer = (float*)d_ws;                          // 512*512*32 fp32 = 33.5 MB
    float* denom = numer + (size_t)512 * NN * DH;         // 512*512 fp32 = 1 MB
    attn_kernel<<<dim3(512), dim3(512), 0, stream>>>(inputs, linear, asrc, atar,
                                                     numer, denom);
    gru_kernel<<<dim3(256), dim3(256), 0, stream>>>(inputs, hidden, bias,
                                                    Whr, Whi, Whm,
                                                    Wir, bir, Wii, bii, Win, bin_,
                                                    numer, denom, (float*)d_out);
}

// Round 10
// 153.843 us; speedup vs baseline: 1.0886x; 1.0886x over previous
//
#include <hip/hip_runtime.h>

#define NN 512
#define DIN 64
#define DH 32
#define HT 264    // h_t row stride for 256 local rows (+8 pad)

typedef __attribute__((ext_vector_type(8))) short short8;
typedef __attribute__((ext_vector_type(4))) short short4v;
typedef __attribute__((ext_vector_type(4))) float f32x4;

__device__ __forceinline__ float bf2f(unsigned short u) {
    return __uint_as_float(((unsigned)u) << 16);
}
__device__ __forceinline__ unsigned short f2bf(float x) {
    unsigned u = __float_as_uint(x);
    u += 0x7FFF + ((u >> 16) & 1);
    return (unsigned short)(u >> 16);
}

// Two blocks per (head,batch) split by j-half; 512 threads, no min-waves.
// CRITICAL: the kb loop must stay ROLLED. R9's kb<8 loop got fully unrolled
// by the compiler -> live-range explosion -> VGPR 128 + scratch spill
// (WRITE 63 MB, occupancy 18%, attn 61 us). R5's 16-iter loop stayed rolled
// at 88 VGPR. unroll(disable) pins that behavior.
__global__ __launch_bounds__(512) void attn_kernel(
    const float* __restrict__ in_g,    // [B,512,64]
    const float* __restrict__ lin_g,   // [H,64,32]
    const float* __restrict__ asrc_g,  // [H,32]
    const float* __restrict__ atar_g,  // [H,32]
    float* __restrict__ numer,         // [512 slices][512][32] raw partial sums
    float* __restrict__ denom)         // [512 slices][512] raw partial denominators
{
    __shared__ unsigned short h_t[DH * HT];          // 16896 B: h_t[c*HT + jloc]
    __shared__ float wsv[DIN], wtv[DIN];             // W @ a_src, W @ a_tar
    __shared__ float s_arr[256], e1s[256], e2s[256]; // local j-half: s, e^s, e^{0.2s}
    __shared__ float cng[NN], e1t[NN], e2t[NN];      // all i: -t, e^t, e^{0.2t}

    const int t = threadIdx.x;
    const int lane = t & 63, wv = t >> 6;
    const int l15 = lane & 15, quad = lane >> 4;
    const int jh   = blockIdx.x & 1;                 // j-half
    const int hIdx = (blockIdx.x >> 1) & 7;
    const int bIdx = blockIdx.x >> 4;
    const int slice = blockIdx.x;

    // ---------- A0a: project attention vectors through W (64x32 each) ----------
    if (t < 128) {
        int d = t & 63;
        const float* av = (t < 64) ? (asrc_g + hIdx * 32) : (atar_g + hIdx * 32);
        const float* lp = lin_g + hIdx * (DIN * DH) + d * DH;
        float a = 0.f;
        #pragma unroll
        for (int k = 0; k < 32; ++k) a += lp[k] * av[k];
        if (t < 64) wsv[d] = a; else wtv[d] = a;
    }
    __syncthreads();

    // ---------- A0b: s,t for all 512 rows directly from x (fp32) ----------
    const float* xb = in_g + (size_t)bIdx * (NN * DIN);
    {
        int r = t;                                   // 512 rows, 512 threads
        const float* xr = xb + r * DIN;
        float ds = 0.f, dt = 0.f;
        #pragma clang loop unroll(disable)
        for (int d0 = 0; d0 < DIN; d0 += 4) {
            f32x4 xv = *(const f32x4*)(xr + d0);
            #pragma unroll
            for (int j = 0; j < 4; ++j) {
                ds += xv[j] * wsv[d0 + j];
                dt += xv[j] * wtv[d0 + j];
            }
        }
        cng[r] = -dt; e1t[r] = expf(dt); e2t[r] = expf(0.2f * dt);
        int rl = r - jh * 256;
        if ((unsigned)rl < 256u) {
            s_arr[rl] = ds; e1s[rl] = expf(ds); e2s[rl] = expf(0.2f * ds);
        }
    }

    // ---------- A1: projection of THIS half's 256 j-rows (16 M-tiles / 8 waves) ----------
    short8 bfrag[2][2];
    {
        const float* lp = lin_g + hIdx * (DIN * DH);
        for (int nt = 0; nt < 2; ++nt)
            for (int ks = 0; ks < 2; ++ks)
                #pragma unroll
                for (int j = 0; j < 8; ++j)
                    bfrag[nt][ks][j] = (short)f2bf(lp[(ks * 32 + quad * 8 + j) * DH + l15 + nt * 16]);
    }
    #pragma clang loop unroll(disable)
    for (int mi = 0; mi < 2; ++mi) {
        int mt = wv * 2 + mi;                        // 16 local M-tiles
        int row = jh * 256 + mt * 16 + l15;          // global j-row
        const float* rp = xb + row * DIN + quad * 8;
        f32x4 x0 = *((const f32x4*)rp);
        f32x4 x1 = *((const f32x4*)(rp + 4));
        f32x4 x2 = *((const f32x4*)(rp + 32));
        f32x4 x3 = *((const f32x4*)(rp + 36));
        short8 a0, a1;
        #pragma unroll
        for (int j = 0; j < 4; ++j) {
            a0[j]     = (short)f2bf(x0[j]);
            a0[4 + j] = (short)f2bf(x1[j]);
            a1[j]     = (short)f2bf(x2[j]);
            a1[4 + j] = (short)f2bf(x3[j]);
        }
        f32x4 c0 = {0.f, 0.f, 0.f, 0.f}, c1 = {0.f, 0.f, 0.f, 0.f};
        c0 = __builtin_amdgcn_mfma_f32_16x16x32_bf16(a0, bfrag[0][0], c0, 0, 0, 0);
        c0 = __builtin_amdgcn_mfma_f32_16x16x32_bf16(a1, bfrag[0][1], c0, 0, 0, 0);
        c1 = __builtin_amdgcn_mfma_f32_16x16x32_bf16(a0, bfrag[1][0], c1, 0, 0, 0);
        c1 = __builtin_amdgcn_mfma_f32_16x16x32_bf16(a1, bfrag[1][1], c1, 0, 0, 0);
        #pragma unroll
        for (int r = 0; r < 4; ++r) {
            int mloc = mt * 16 + quad * 4 + r;       // local row 0..255
            h_t[l15 * HT + mloc]        = f2bf(c0[r]);
            h_t[(l15 + 16) * HT + mloc] = f2bf(c1[r]);
        }
    }
    __syncthreads();

    // ---------- B: all 512 i-rows x this half's 256 j (32 row-tiles / 8 waves) ----------
    float cn[4], t1v[4], t2v[4];
    int iR[4], iRl[4];
    #pragma unroll
    for (int rt = 0; rt < 4; ++rt) {
        int rw = (wv * 4 + rt) * 16 + l15;           // global i-row
        iR[rt] = rw; iRl[rt] = rw - jh * 256;
        cn[rt] = cng[rw]; t1v[rt] = e1t[rw]; t2v[rt] = e2t[rw];
    }
    f32x4 acc[4][2];
    float dacc[4];
    #pragma unroll
    for (int rt = 0; rt < 4; ++rt) {
        acc[rt][0] = (f32x4){0.f, 0.f, 0.f, 0.f};
        acc[rt][1] = (f32x4){0.f, 0.f, 0.f, 0.f};
        dacc[rt] = 0.f;
    }

    #pragma clang loop unroll(disable)
    for (int kb = 0; kb < 8; ++kb) {
        const int j0 = kb * 32 + quad * 8;           // local j
        short8 b0 = *(const short8*)&h_t[l15 * HT + j0];
        short8 b1 = *(const short8*)&h_t[(l15 + 16) * HT + j0];
        #pragma unroll
        for (int rt = 0; rt < 4; ++rt) {
            const bool selfkb = ((iRl[rt] >> 5) == kb);   // self-edge in this j-tile?
            float w8[8];
            // jj 0..3 from the lo-half tables, then 4..7 — sequential halves
            // keep concurrent live f32x4 count low (anti-spill).
            {
                f32x4 sv = *(const f32x4*)&s_arr[j0];
                f32x4 ev = *(const f32x4*)&e1s[j0];
                f32x4 fv = *(const f32x4*)&e2s[j0];
                #pragma unroll
                for (int jj = 0; jj < 4; ++jj) {
                    float w = (sv[jj] > cn[rt]) ? t1v[rt] * ev[jj] : t2v[rt] * fv[jj];
                    if (selfkb && (j0 + jj == iRl[rt])) w = 0.f;
                    dacc[rt] += w;
                    w8[jj] = w;
                }
            }
            {
                f32x4 sv = *(const f32x4*)&s_arr[j0 + 4];
                f32x4 ev = *(const f32x4*)&e1s[j0 + 4];
                f32x4 fv = *(const f32x4*)&e2s[j0 + 4];
                #pragma unroll
                for (int jj = 0; jj < 4; ++jj) {
                    float w = (sv[jj] > cn[rt]) ? t1v[rt] * ev[jj] : t2v[rt] * fv[jj];
                    if (selfkb && (j0 + 4 + jj == iRl[rt])) w = 0.f;
                    dacc[rt] += w;
                    w8[4 + jj] = w;
                }
            }
            union { unsigned u[4]; short8 s8; } au;
            #pragma unroll
            for (int pp = 0; pp < 4; ++pp) {
                unsigned lo = __float_as_uint(w8[2 * pp])     + 0x8000u;
                unsigned hi = __float_as_uint(w8[2 * pp + 1]) + 0x8000u;
                au.u[pp] = (lo >> 16) | (hi & 0xffff0000u);
            }
            acc[rt][0] = __builtin_amdgcn_mfma_f32_16x16x32_bf16(au.s8, b0, acc[rt][0], 0, 0, 0);
            acc[rt][1] = __builtin_amdgcn_mfma_f32_16x16x32_bf16(au.s8, b1, acc[rt][1], 0, 0, 0);
        }
    }

    // partial denominator: reduce the 4 quads, write raw
    #pragma unroll
    for (int rt = 0; rt < 4; ++rt) {
        float D = dacc[rt];
        D += __shfl_xor(D, 16, 64);
        D += __shfl_xor(D, 32, 64);
        if (quad == 0) denom[(size_t)slice * NN + iR[rt]] = D;
    }

    // partial numerator, unscaled
    float* nb = numer + (size_t)slice * (NN * DH);
    #pragma unroll
    for (int rt = 0; rt < 4; ++rt) {
        #pragma unroll
        for (int half = 0; half < 2; ++half) {
            #pragma unroll
            for (int r = 0; r < 4; ++r) {
                int row = (wv * 4 + rt) * 16 + quad * 4 + r;
                nb[row * DH + half * 16 + l15] = acc[rt][half][r];
            }
        }
    }
}

// GRU-style gated update. 256 blocks x 256 threads, 64 rows/block.
// Combines the 16 partial slices (8 heads x 2 j-halves) of numer/denom.
__global__ __launch_bounds__(256) void gru_kernel(
    const float* __restrict__ in_g,
    const float* __restrict__ hid_g,
    const float* __restrict__ bias_g,
    const float* __restrict__ Whr, const float* __restrict__ Whi,
    const float* __restrict__ Whm,
    const float* __restrict__ Wir, const float* __restrict__ bir,
    const float* __restrict__ Wii, const float* __restrict__ bii,
    const float* __restrict__ Win, const float* __restrict__ bin_,
    const float* __restrict__ numer,   // [512][512][32]
    const float* __restrict__ denom,   // [512][512]
    float* __restrict__ out_g)
{
    __shared__ float xs[64 * 100];                // cols 0..63 = x, 64..95 = tanh(msum+bias)
    __shared__ unsigned short WtL[3 * 32 * 100];  // Wt[g][k][d] bf16 (96 d's used)
    __shared__ float Dl[64 * 8];                  // 0.125/(D0+D1) per (row,head)

    const int t = threadIdx.x;
    const int rowbase = blockIdx.x * 64;
    const int bslice = blockIdx.x >> 3;           // batch of this block
    const int r0 = (blockIdx.x & 7) * 64;         // row offset within batch

    for (int idx = t; idx < 1024; idx += 256) {
        int fi = idx * 4;
        int row = fi >> 6, d = fi & 63;
        f32x4 v = *(const f32x4*)&in_g[(size_t)(rowbase + row) * 64 + d];
        *(f32x4*)&xs[row * 100 + d] = v;
    }
    for (int idx = t; idx < 512; idx += 256) {    // (row, head) -> combined 1/D
        int row = idx >> 3, h = idx & 7;
        int sl0 = (bslice * 8 + h) * 2;
        float D0 = denom[(size_t)sl0 * NN + (r0 + row)];
        float D1 = denom[(size_t)(sl0 + 1) * NN + (r0 + row)];
        Dl[row * 8 + h] = 0.125f / (D0 + D1);
    }
    for (int idx = t; idx < 9216; idx += 256) {
        int g = idx / 3072, rem = idx % 3072;
        int d = rem >> 5, k2 = rem & 31;
        float v;
        if (g == 0) v = (d < 64) ? Wir[d * 32 + k2] : Whr[(d - 64) * 32 + k2];
        else if (g == 1) v = (d < 64) ? Wii[d * 32 + k2] : Whi[(d - 64) * 32 + k2];
        else v = (d < 64) ? Win[d * 32 + k2] : Whm[(d - 64) * 32 + k2];
        WtL[(g * 32 + k2) * 100 + d] = f2bf(v);
    }
    __syncthreads();
    for (int idx = t; idx < 2048; idx += 256) {   // msum = sum_h (n0+n1)*Dl
        int row = idx >> 5, k2 = idx & 31;
        float ssum = 0.f;
        #pragma unroll
        for (int h = 0; h < 8; ++h) {
            size_t a0 = ((size_t)(bslice * 8 + h) * 2) * (NN * DH) + (size_t)(r0 + row) * DH + k2;
            ssum += (numer[a0] + numer[a0 + (size_t)NN * DH]) * Dl[row * 8 + h];
        }
        xs[row * 100 + 64 + k2] = tanhf(ssum + bias_g[k2]);
    }
    __syncthreads();

    const int k = t & 31, rg = t >> 5;
    const unsigned short* wp0 = &WtL[(0 * 32 + k) * 100];
    const unsigned short* wp1 = &WtL[(1 * 32 + k) * 100];
    const unsigned short* wp2 = &WtL[(2 * 32 + k) * 100];

    float pr[8], pi[8], xn[8], hm[8];
    #pragma unroll
    for (int r = 0; r < 8; ++r) { pr[r] = 0.f; pi[r] = 0.f; xn[r] = 0.f; hm[r] = 0.f; }

    for (int d0 = 0; d0 < 64; d0 += 4) {
        short4v wr4 = *(const short4v*)&wp0[d0];
        short4v wi4 = *(const short4v*)&wp1[d0];
        short4v wn4 = *(const short4v*)&wp2[d0];
        float wr[4], wi[4], wn[4];
        #pragma unroll
        for (int jj = 0; jj < 4; ++jj) {
            wr[jj] = bf2f((unsigned short)wr4[jj]);
            wi[jj] = bf2f((unsigned short)wi4[jj]);
            wn[jj] = bf2f((unsigned short)wn4[jj]);
        }
        #pragma unroll
        for (int r = 0; r < 8; ++r) {
            f32x4 xv = *(const f32x4*)&xs[(rg * 8 + r) * 100 + d0];
            #pragma unroll
            for (int jj = 0; jj < 4; ++jj) {
                pr[r] += xv[jj] * wr[jj];
                pi[r] += xv[jj] * wi[jj];
                xn[r] += xv[jj] * wn[jj];
            }
        }
    }
    for (int d0 = 64; d0 < 96; d0 += 4) {
        short4v wr4 = *(const short4v*)&wp0[d0];
        short4v wi4 = *(const short4v*)&wp1[d0];
        short4v wn4 = *(const short4v*)&wp2[d0];
        float wr[4], wi[4], wn[4];
        #pragma unroll
        for (int jj = 0; jj < 4; ++jj) {
            wr[jj] = bf2f((unsigned short)wr4[jj]);
            wi[jj] = bf2f((unsigned short)wi4[jj]);
            wn[jj] = bf2f((unsigned short)wn4[jj]);
        }
        #pragma unroll
        for (int r = 0; r < 8; ++r) {
            f32x4 xv = *(const f32x4*)&xs[(rg * 8 + r) * 100 + d0];
            #pragma unroll
            for (int jj = 0; jj < 4; ++jj) {
                pr[r] += xv[jj] * wr[jj];
                pi[r] += xv[jj] * wi[jj];
                hm[r] += xv[jj] * wn[jj];
            }
        }
    }

    const float bir_k = bir[k], bii_k = bii[k], bin_k = bin_[k];
    #pragma unroll
    for (int r = 0; r < 8; ++r) {
        int row = rowbase + rg * 8 + r;
        float m  = 1.f / (1.f + expf(-(pr[r] + bir_k)));
        float ig = 1.f / (1.f + expf(-(pi[r] + bii_k)));
        float nn = tanhf(xn[r] + bin_k + m * hm[r]);
        float ho = hid_g[(size_t)row * 32 + k];
        out_g[(size_t)row * 32 + k] = ig * nn + (1.f - ig) * ho;
    }
}

extern "C" void kernel_launch(void* const* d_in, const int* in_sizes, int n_in,
                              void* d_out, int out_size, void* d_ws, size_t ws_size,
                              hipStream_t stream)
{
    const float* inputs = (const float*)d_in[0];
    const float* hidden = (const float*)d_in[1];
    const float* linear = (const float*)d_in[2];
    const float* bias   = (const float*)d_in[3];
    const float* asrc   = (const float*)d_in[4];
    const float* atar   = (const float*)d_in[5];
    const float* Whr    = (const float*)d_in[6];
    const float* Whi    = (const float*)d_in[7];
    const float* Whm    = (const float*)d_in[8];
    const float* Wir    = (const float*)d_in[9];
    const float* bir    = (const float*)d_in[10];
    const float* Wii    = (const float*)d_in[11];
    const float* bii    = (const float*)d_in[12];
    const float* Win    = (const float*)d_in[13];
    const float* bin_   = (const float*)d_in[14];

    float* numer = (float*)d_ws;                          // 512*512*32 fp32 = 33.5 MB
    float* denom = numer + (size_t)512 * NN * DH;         // 512*512 fp32 = 1 MB
    attn_kernel<<<dim3(512), dim3(512), 0, stream>>>(inputs, linear, asrc, atar,
                                                     numer, denom);
    gru_kernel<<<dim3(256), dim3(256), 0, stream>>>(inputs, hidden, bias,
                                                    Whr, Whi, Whm,
                                                    Wir, bir, Wii, bii, Win, bin_,
                                                    numer, denom, (float*)d_out);
}